// Round 1
// baseline (1815.371 us; speedup 1.0000x reference)
//
#include <hip/hip_runtime.h>

#define N_NODES 50000
#define N_EDGES 800000
#define IN_C 8
#define OUT_C 16
#define EDGE_F 8
#define HEADS 4
#define HID 64
#define GDIM (HEADS*HID)   // 256
#define FINAL 128
#define NEG_SLOPE 0.2f

// ---- float <-> monotonic uint encoding for atomicMax on floats ----
__device__ __forceinline__ unsigned fenc(float f) {
    unsigned u = __float_as_uint(f);
    return (u & 0x80000000u) ? ~u : (u | 0x80000000u);
}
__device__ __forceinline__ float fdec(unsigned u) {
    return (u & 0x80000000u) ? __uint_as_float(u & 0x7fffffffu)
                             : __uint_as_float(~u);
}

// K1: NNConv edge pass: msg = x[src] @ (edge_attr @ mlp_w + mlp_b), atomic into agg[dst]
__global__ __launch_bounds__(256) void k1_nnconv_edge(
    const float* __restrict__ x, const float* __restrict__ ea,
    const int* __restrict__ src, const int* __restrict__ dst,
    const float* __restrict__ mlp_w, const float* __restrict__ mlp_b,
    float* __restrict__ agg)
{
    __shared__ float smw[EDGE_F * IN_C * OUT_C];  // 1024
    __shared__ float smb[IN_C * OUT_C];           // 128
    for (int i = threadIdx.x; i < EDGE_F * IN_C * OUT_C; i += blockDim.x) smw[i] = mlp_w[i];
    for (int i = threadIdx.x; i < IN_C * OUT_C; i += blockDim.x) smb[i] = mlp_b[i];
    __syncthreads();

    int e = blockIdx.x * blockDim.x + threadIdx.x;
    if (e >= N_EDGES) return;
    int s = src[e]; if (s < 0) s = 0; if (s >= N_NODES) s = N_NODES - 1;
    int d = dst[e]; if (d < 0) d = 0; if (d >= N_NODES) d = N_NODES - 1;

    float xe[IN_C], att[EDGE_F];
#pragma unroll
    for (int i = 0; i < IN_C; i++) xe[i] = x[s * IN_C + i];
#pragma unroll
    for (int f = 0; f < EDGE_F; f++) att[f] = ea[e * EDGE_F + f];

    float msg[OUT_C];
#pragma unroll
    for (int o = 0; o < OUT_C; o++) msg[o] = 0.f;

#pragma unroll
    for (int i = 0; i < IN_C; i++) {
#pragma unroll
        for (int o = 0; o < OUT_C; o++) {
            float w = smb[i * OUT_C + o];
#pragma unroll
            for (int f = 0; f < EDGE_F; f++)
                w += att[f] * smw[f * (IN_C * OUT_C) + i * OUT_C + o];
            msg[o] += xe[i] * w;
        }
    }
#pragma unroll
    for (int o = 0; o < OUT_C; o++)
        atomicAdd(&agg[d * OUT_C + o], msg[o]);
}

// K2: node pass: h = relu(x@root + agg + bias); g = h@gat_lin; a_src/a_dst per head
__global__ __launch_bounds__(256) void k2_node(
    const float* __restrict__ x, const float* __restrict__ agg,
    const float* __restrict__ ecc_root, const float* __restrict__ ecc_bias,
    const float* __restrict__ gat_lin,
    const float* __restrict__ att_src_w, const float* __restrict__ att_dst_w,
    float* __restrict__ g, float* __restrict__ asrc, float* __restrict__ adst)
{
    int n = blockIdx.x;
    int tid = threadIdx.x;
    __shared__ float sh[OUT_C];
    if (tid < OUT_C) {
        float v = ecc_bias[tid] + agg[n * OUT_C + tid];
#pragma unroll
        for (int i = 0; i < IN_C; i++) v += x[n * IN_C + i] * ecc_root[i * OUT_C + tid];
        sh[tid] = v > 0.f ? v : 0.f;
    }
    __syncthreads();
    int head = tid >> 6, d = tid & 63;
    float gv = 0.f;
#pragma unroll
    for (int k = 0; k < OUT_C; k++) gv += sh[k] * gat_lin[k * GDIM + tid];
    g[n * GDIM + tid] = gv;
    float vs = gv * att_src_w[tid];
    float vd = gv * att_dst_w[tid];
#pragma unroll
    for (int off = 32; off > 0; off >>= 1) {
        vs += __shfl_down(vs, off);
        vd += __shfl_down(vd, off);
    }
    if (d == 0) {
        asrc[n * HEADS + head] = vs;
        adst[n * HEADS + head] = vd;
    }
}

// K3: e = leaky_relu(a_src[src] + a_dst[dst]); store raw e; atomicMax encoded per dst
__global__ __launch_bounds__(256) void k3_att_max(
    const int* __restrict__ src, const int* __restrict__ dst,
    const float* __restrict__ asrc, const float* __restrict__ adst,
    float* __restrict__ ebuf, unsigned* __restrict__ emax)
{
    int e = blockIdx.x * blockDim.x + threadIdx.x;
    if (e >= N_EDGES) return;
    int s = src[e]; if (s < 0) s = 0; if (s >= N_NODES) s = N_NODES - 1;
    int d = dst[e]; if (d < 0) d = 0; if (d >= N_NODES) d = N_NODES - 1;
#pragma unroll
    for (int h = 0; h < HEADS; h++) {
        float v = asrc[s * HEADS + h] + adst[d * HEADS + h];
        v = v > 0.f ? v : NEG_SLOPE * v;
        ebuf[e * HEADS + h] = v;
        atomicMax(&emax[d * HEADS + h], fenc(v));
    }
}

// K4: e_exp = exp(e - e_max[dst]); atomicAdd denom
__global__ __launch_bounds__(256) void k4_att_exp(
    const int* __restrict__ dst, const unsigned* __restrict__ emax,
    float* __restrict__ ebuf, float* __restrict__ denom)
{
    int e = blockIdx.x * blockDim.x + threadIdx.x;
    if (e >= N_EDGES) return;
    int d = dst[e]; if (d < 0) d = 0; if (d >= N_NODES) d = N_NODES - 1;
#pragma unroll
    for (int h = 0; h < HEADS; h++) {
        unsigned u = emax[d * HEADS + h];
        float m = u ? fdec(u) : 0.f;   // no-edge segments -> 0 (matches isfinite fixup)
        float v = expf(ebuf[e * HEADS + h] - m);
        ebuf[e * HEADS + h] = v;
        atomicAdd(&denom[d * HEADS + h], v);
    }
}

// K5: out[dst] += alpha * g[src]; one wave (64 lanes) per edge, lane = hid dim
__global__ __launch_bounds__(256) void k5_gat_agg(
    const int* __restrict__ src, const int* __restrict__ dst,
    const float* __restrict__ g, const float* __restrict__ ebuf,
    const float* __restrict__ denom, float* __restrict__ outg)
{
    int lane = threadIdx.x & 63;
    int e = blockIdx.x * (blockDim.x >> 6) + (threadIdx.x >> 6);
    if (e >= N_EDGES) return;
    int s = src[e]; if (s < 0) s = 0; if (s >= N_NODES) s = N_NODES - 1;
    int d = dst[e]; if (d < 0) d = 0; if (d >= N_NODES) d = N_NODES - 1;
#pragma unroll
    for (int h = 0; h < HEADS; h++) {
        float alpha = ebuf[e * HEADS + h] / (denom[d * HEADS + h] + 1e-16f);
        atomicAdd(&outg[d * GDIM + h * HID + lane],
                  alpha * g[s * GDIM + h * HID + lane]);
    }
}

// K6: y = relu(outg + gat_bias) @ fc_w + fc_b   -- tiled fp32 GEMM
// BM=64 rows/block, BK=16, 256 threads, 8x4 register tile each
#define BM 64
#define BK6 16
__global__ __launch_bounds__(256) void k6_final(
    const float* __restrict__ outg, const float* __restrict__ gat_bias,
    const float* __restrict__ fc_w, const float* __restrict__ fc_b,
    float* __restrict__ y)
{
    __shared__ float sA[BK6][BM + 4];    // transposed A tile, padded
    __shared__ float sW[BK6][FINAL];
    int tid = threadIdx.x;
    int r0 = blockIdx.x * BM;
    int tcol = (tid & 31) * 4;
    int trow = (tid >> 5) * 8;

    float acc[8][4];
#pragma unroll
    for (int r = 0; r < 8; r++)
#pragma unroll
        for (int c = 0; c < 4; c++) acc[r][c] = 0.f;

    int ar = tid >> 2;          // 0..63
    int ak = (tid & 3) * 4;     // 0,4,8,12

    for (int k0 = 0; k0 < GDIM; k0 += BK6) {
        // A tile: relu(outg + gat_bias), transposed into sA[k][row]
        int row = r0 + ar;
        float4 av = make_float4(0.f, 0.f, 0.f, 0.f);
        if (row < N_NODES)
            av = *(const float4*)&outg[row * GDIM + k0 + ak];
        float4 bv = *(const float4*)&gat_bias[k0 + ak];
        av.x = fmaxf(av.x + bv.x, 0.f);
        av.y = fmaxf(av.y + bv.y, 0.f);
        av.z = fmaxf(av.z + bv.z, 0.f);
        av.w = fmaxf(av.w + bv.w, 0.f);
        sA[ak + 0][ar] = av.x;
        sA[ak + 1][ar] = av.y;
        sA[ak + 2][ar] = av.z;
        sA[ak + 3][ar] = av.w;
        // W tile
#pragma unroll
        for (int p = 0; p < 2; p++) {
            int kk = (tid >> 5) + p * 8;
            int c = (tid & 31) * 4;
            *(float4*)&sW[kk][c] = *(const float4*)&fc_w[(k0 + kk) * FINAL + c];
        }
        __syncthreads();
#pragma unroll
        for (int kk = 0; kk < BK6; kk++) {
            float4 w = *(const float4*)&sW[kk][tcol];
            float4 a0 = *(const float4*)&sA[kk][trow];
            float4 a1 = *(const float4*)&sA[kk][trow + 4];
            float a[8] = {a0.x, a0.y, a0.z, a0.w, a1.x, a1.y, a1.z, a1.w};
#pragma unroll
            for (int r = 0; r < 8; r++) {
                acc[r][0] += a[r] * w.x;
                acc[r][1] += a[r] * w.y;
                acc[r][2] += a[r] * w.z;
                acc[r][3] += a[r] * w.w;
            }
        }
        __syncthreads();
    }

    float4 fb = *(const float4*)&fc_b[tcol];
#pragma unroll
    for (int r = 0; r < 8; r++) {
        int row = r0 + trow + r;
        if (row < N_NODES) {
            float4 res = make_float4(acc[r][0] + fb.x, acc[r][1] + fb.y,
                                     acc[r][2] + fb.z, acc[r][3] + fb.w);
            *(float4*)&y[row * FINAL + tcol] = res;
        }
    }
}

extern "C" void kernel_launch(void* const* d_in, const int* in_sizes, int n_in,
                              void* d_out, int out_size, void* d_ws, size_t ws_size,
                              hipStream_t stream)
{
    const float* x        = (const float*)d_in[0];
    const int*   ei       = (const int*)d_in[1];
    const float* ea       = (const float*)d_in[2];
    const float* ecc_root = (const float*)d_in[3];
    const float* ecc_bias = (const float*)d_in[4];
    const float* mlp_w    = (const float*)d_in[5];
    const float* mlp_b    = (const float*)d_in[6];
    const float* gat_lin  = (const float*)d_in[7];
    const float* att_src  = (const float*)d_in[8];
    const float* att_dst  = (const float*)d_in[9];
    const float* gat_bias = (const float*)d_in[10];
    const float* fc_w     = (const float*)d_in[11];
    const float* fc_b     = (const float*)d_in[12];
    float* y = (float*)d_out;

    const int* src = ei;
    const int* dst = ei + N_EDGES;

    // workspace layout (floats)
    float* ws = (float*)d_ws;
    float*    agg   = ws;                          // N*16
    float*    g     = agg + (size_t)N_NODES * OUT_C;     // N*256
    float*    asrc  = g + (size_t)N_NODES * GDIM;        // N*4
    float*    adst  = asrc + (size_t)N_NODES * HEADS;    // N*4
    unsigned* emax  = (unsigned*)(adst + (size_t)N_NODES * HEADS); // N*4
    float*    denom = (float*)(emax + (size_t)N_NODES * HEADS);    // N*4
    float*    ebuf  = denom + (size_t)N_NODES * HEADS;   // E*4
    float*    outg  = ebuf + (size_t)N_EDGES * HEADS;    // N*256

    hipMemsetAsync(agg, 0, sizeof(float) * N_NODES * OUT_C, stream);
    hipMemsetAsync(emax, 0, sizeof(unsigned) * N_NODES * HEADS, stream);
    hipMemsetAsync(denom, 0, sizeof(float) * N_NODES * HEADS, stream);
    hipMemsetAsync(outg, 0, sizeof(float) * (size_t)N_NODES * GDIM, stream);

    int eb = (N_EDGES + 255) / 256;
    k1_nnconv_edge<<<eb, 256, 0, stream>>>(x, ea, src, dst, mlp_w, mlp_b, agg);
    k2_node<<<N_NODES, 256, 0, stream>>>(x, agg, ecc_root, ecc_bias, gat_lin,
                                         att_src, att_dst, g, asrc, adst);
    k3_att_max<<<eb, 256, 0, stream>>>(src, dst, asrc, adst, ebuf, emax);
    k4_att_exp<<<eb, 256, 0, stream>>>(dst, emax, ebuf, denom);
    k5_gat_agg<<<(N_EDGES * 64 + 255) / 256, 256, 0, stream>>>(src, dst, g, ebuf, denom, outg);
    k6_final<<<(N_NODES + BM - 1) / BM, 256, 0, stream>>>(outg, gat_bias, fc_w, fc_b, y);
}

// Round 2
// 485.924 us; speedup vs baseline: 3.7359x; 3.7359x over previous
//
#include <hip/hip_runtime.h>

#define N_NODES 50000
#define N_EDGES 800000
#define IN_C 8
#define OUT_C 16
#define EDGE_F 8
#define HEADS 4
#define HID 64
#define GDIM (HEADS*HID)   // 256
#define FINAL 128
#define NEG_SLOPE 0.2f
#define NBLK 196           // ceil(N_NODES/256)

__device__ __forceinline__ int clampn(int v) {
    return v < 0 ? 0 : (v >= N_NODES ? N_NODES - 1 : v);
}

// ---------- CSR build ----------
__global__ __launch_bounds__(256) void k_hist(const int* __restrict__ dst,
                                              int* __restrict__ cnt)
{
    int e = blockIdx.x * 256 + threadIdx.x;
    if (e >= N_EDGES) return;
    atomicAdd(&cnt[clampn(dst[e])], 1);
}

__global__ __launch_bounds__(256) void k_part(const int* __restrict__ cnt,
                                              int* __restrict__ part)
{
    int i = blockIdx.x * 256 + threadIdx.x;
    int v = (i < N_NODES) ? cnt[i] : 0;
#pragma unroll
    for (int off = 32; off; off >>= 1) v += __shfl_down(v, off);
    __shared__ int ws[4];
    if ((threadIdx.x & 63) == 0) ws[threadIdx.x >> 6] = v;
    __syncthreads();
    if (threadIdx.x == 0) part[blockIdx.x] = ws[0] + ws[1] + ws[2] + ws[3];
}

__global__ __launch_bounds__(256) void k_scan1(const int* __restrict__ part,
                                               int* __restrict__ partscan)
{
    int t = threadIdx.x;
    int v = (t < NBLK) ? part[t] : 0;
    int lane = t & 63, wid = t >> 6;
    int incl = v;
#pragma unroll
    for (int off = 1; off < 64; off <<= 1) {
        int u = __shfl_up(incl, off);
        if (lane >= off) incl += u;
    }
    __shared__ int wsum[4];
    if (lane == 63) wsum[wid] = incl;
    __syncthreads();
    int add = 0;
    for (int w = 0; w < wid; w++) add += wsum[w];
    partscan[t] = incl - v + add;   // exclusive
}

__global__ __launch_bounds__(256) void k_add(const int* __restrict__ cnt,
                                             const int* __restrict__ partscan,
                                             int* __restrict__ offs,
                                             int* __restrict__ cursor)
{
    int i = blockIdx.x * 256 + threadIdx.x;
    int v = (i < N_NODES) ? cnt[i] : 0;
    int lane = threadIdx.x & 63, wid = threadIdx.x >> 6;
    int incl = v;
#pragma unroll
    for (int off = 1; off < 64; off <<= 1) {
        int u = __shfl_up(incl, off);
        if (lane >= off) incl += u;
    }
    __shared__ int wsum[4];
    if (lane == 63) wsum[wid] = incl;
    __syncthreads();
    int add = partscan[blockIdx.x];
    for (int w = 0; w < wid; w++) add += wsum[w];
    if (i < N_NODES) {
        int ex = incl - v + add;
        offs[i] = ex;
        cursor[i] = ex;
    }
    if (i == 0) offs[N_NODES] = N_EDGES;
}

__global__ __launch_bounds__(256) void k_scatter(const int* __restrict__ dst,
                                                 int* __restrict__ cursor,
                                                 int* __restrict__ eidx)
{
    int e = blockIdx.x * 256 + threadIdx.x;
    if (e >= N_EDGES) return;
    int p = atomicAdd(&cursor[clampn(dst[e])], 1);
    eidx[p] = e;
}

// ---------- K1b: per-edge NNConv message (no atomics) ----------
__global__ __launch_bounds__(256) void k1b_msg(
    const float* __restrict__ x, const float* __restrict__ ea,
    const int* __restrict__ src,
    const float* __restrict__ mlp_w, const float* __restrict__ mlp_b,
    float* __restrict__ msgbuf)
{
    __shared__ float smw[EDGE_F * IN_C * OUT_C];  // 1024
    __shared__ float smb[IN_C * OUT_C];           // 128
    for (int i = threadIdx.x; i < EDGE_F * IN_C * OUT_C; i += 256) smw[i] = mlp_w[i];
    for (int i = threadIdx.x; i < IN_C * OUT_C; i += 256) smb[i] = mlp_b[i];
    __syncthreads();

    int e = blockIdx.x * 256 + threadIdx.x;
    if (e >= N_EDGES) return;
    int s = clampn(src[e]);

    float xe[IN_C], att[EDGE_F];
#pragma unroll
    for (int i = 0; i < IN_C; i++) xe[i] = x[s * IN_C + i];
#pragma unroll
    for (int f = 0; f < EDGE_F; f++) att[f] = ea[e * EDGE_F + f];

    float msg[OUT_C];
#pragma unroll
    for (int o = 0; o < OUT_C; o++) msg[o] = 0.f;
#pragma unroll
    for (int i = 0; i < IN_C; i++) {
#pragma unroll
        for (int o = 0; o < OUT_C; o++) {
            float w = smb[i * OUT_C + o];
#pragma unroll
            for (int f = 0; f < EDGE_F; f++)
                w += att[f] * smw[f * (IN_C * OUT_C) + i * OUT_C + o];
            msg[o] += xe[i] * w;
        }
    }
#pragma unroll
    for (int o = 0; o < OUT_C; o += 4)
        *(float4*)&msgbuf[(size_t)e * OUT_C + o] =
            make_float4(msg[o], msg[o+1], msg[o+2], msg[o+3]);
}

// ---------- K2b: per-node (one wave): agg gather + h + g + attention logits ----------
__global__ __launch_bounds__(256) void k2b_node(
    const float* __restrict__ x, const float* __restrict__ msgbuf,
    const int* __restrict__ offs, const int* __restrict__ eidx,
    const float* __restrict__ ecc_root, const float* __restrict__ ecc_bias,
    const float* __restrict__ gat_lin,
    const float* __restrict__ att_src_w, const float* __restrict__ att_dst_w,
    float* __restrict__ g, float* __restrict__ asrc, float* __restrict__ adst)
{
    int wid = threadIdx.x >> 6, lane = threadIdx.x & 63;
    int n = blockIdx.x * 4 + wid;
    if (n >= N_NODES) return;

    int o = lane & 15, q = lane >> 4;     // 4 edge-groups x 16 outputs
    int beg = offs[n], end = offs[n + 1];

    float aggv = 0.f;
    for (int j = beg + q; j < end; j += 4) {
        int e = eidx[j];
        aggv += msgbuf[(size_t)e * OUT_C + o];
    }
    aggv += __shfl_down(aggv, 32);
    aggv += __shfl_down(aggv, 16);        // lanes 0..15 hold per-o totals

    float hv = 0.f;
    if (lane < 16) {
        float v = ecc_bias[o] + aggv;
#pragma unroll
        for (int i = 0; i < IN_C; i++) v += x[n * IN_C + i] * ecc_root[i * OUT_C + o];
        hv = fmaxf(v, 0.f);
    }

    float gv[4] = {0.f, 0.f, 0.f, 0.f};
#pragma unroll
    for (int k = 0; k < OUT_C; k++) {
        float hk = __shfl(hv, k);
#pragma unroll
        for (int j = 0; j < 4; j++)
            gv[j] += hk * gat_lin[k * GDIM + j * 64 + lane];
    }
#pragma unroll
    for (int j = 0; j < 4; j++) g[(size_t)n * GDIM + j * 64 + lane] = gv[j];

    float vs[4], vd[4];
#pragma unroll
    for (int j = 0; j < 4; j++) {
        vs[j] = gv[j] * att_src_w[j * 64 + lane];
        vd[j] = gv[j] * att_dst_w[j * 64 + lane];
    }
#pragma unroll
    for (int off = 32; off; off >>= 1) {
#pragma unroll
        for (int j = 0; j < 4; j++) {
            vs[j] += __shfl_down(vs[j], off);
            vd[j] += __shfl_down(vd[j], off);
        }
    }
    if (lane == 0) {
#pragma unroll
        for (int j = 0; j < 4; j++) {
            asrc[n * HEADS + j] = vs[j];
            adst[n * HEADS + j] = vd[j];
        }
    }
}

// ---------- K_gat: fused segment softmax + aggregate (block per node) ----------
__global__ __launch_bounds__(256) void k_gat(
    const int* __restrict__ offs, const int* __restrict__ eidx,
    const int* __restrict__ src,
    const float* __restrict__ asrc, const float* __restrict__ adst,
    const float* __restrict__ g, float* __restrict__ outg)
{
    int n = blockIdx.x;
    int t = threadIdx.x;
    int beg = offs[n], deg = offs[n + 1] - beg;

    __shared__ float s_adst[HEADS];
    __shared__ float s_m[HEADS];
    __shared__ float s_den[HEADS];
    __shared__ float s_mw[4][HEADS];
    __shared__ float s_al[64 * HEADS];
    __shared__ int   s_sid[64];

    int j = t >> 2, h = t & 3;   // 64 edge-workers x 4 heads
    int wid = t >> 6;
    if (t < HEADS) s_adst[t] = adst[n * HEADS + t];
    __syncthreads();

    // pass A: per-head max of leaky(asrc[s]+adst[n])
    float m = -1e30f;
    for (int k = j; k < deg; k += 64) {
        int s = clampn(src[eidx[beg + k]]);
        float v = asrc[s * HEADS + h] + s_adst[h];
        v = v > 0.f ? v : NEG_SLOPE * v;
        m = fmaxf(m, v);
    }
#pragma unroll
    for (int mask = 4; mask < 64; mask <<= 1) m = fmaxf(m, __shfl_xor(m, mask));
    if ((t & 63) < 4) s_mw[wid][t & 3] = m;
    __syncthreads();
    if (t < HEADS) {
        float mm = fmaxf(fmaxf(s_mw[0][t], s_mw[1][t]), fmaxf(s_mw[2][t], s_mw[3][t]));
        s_m[t] = (deg > 0) ? mm : 0.f;
    }
    __syncthreads();

    // pass B: unnormalized accumulation + denom
    int head = t >> 6;           // accumulation role: dim t of 256
    float acc = 0.f;
    float denp = 0.f;
    for (int c0 = 0; c0 < deg; c0 += 64) {
        int nc = min(64, deg - c0);
        if (j < nc) {
            int e = eidx[beg + c0 + j];
            int s = clampn(src[e]);
            if (h == 0) s_sid[j] = s;
            float v = asrc[s * HEADS + h] + s_adst[h];
            v = v > 0.f ? v : NEG_SLOPE * v;
            float p = __expf(v - s_m[h]);
            s_al[j * HEADS + h] = p;
            denp += p;
        }
        __syncthreads();
        for (int k = 0; k < nc; k++) {
            int s = s_sid[k];
            acc += s_al[k * HEADS + head] * g[(size_t)s * GDIM + t];
        }
        __syncthreads();
    }
#pragma unroll
    for (int mask = 4; mask < 64; mask <<= 1) denp += __shfl_xor(denp, mask);
    if ((t & 63) < 4) s_mw[wid][t & 3] = denp;
    __syncthreads();
    if (t < HEADS) s_den[t] = s_mw[0][t] + s_mw[1][t] + s_mw[2][t] + s_mw[3][t];
    __syncthreads();

    outg[(size_t)n * GDIM + t] = acc / (s_den[head] + 1e-16f);
}

// ---------- K6: y = relu(outg + gat_bias) @ fc_w + fc_b ----------
#define BM 64
#define BK6 16
__global__ __launch_bounds__(256) void k6_final(
    const float* __restrict__ outg, const float* __restrict__ gat_bias,
    const float* __restrict__ fc_w, const float* __restrict__ fc_b,
    float* __restrict__ y)
{
    __shared__ float sA[BK6][BM + 4];
    __shared__ float sW[BK6][FINAL];
    int tid = threadIdx.x;
    int r0 = blockIdx.x * BM;
    int tcol = (tid & 31) * 4;
    int trow = (tid >> 5) * 8;

    float acc[8][4];
#pragma unroll
    for (int r = 0; r < 8; r++)
#pragma unroll
        for (int c = 0; c < 4; c++) acc[r][c] = 0.f;

    int ar = tid >> 2;
    int ak = (tid & 3) * 4;

    for (int k0 = 0; k0 < GDIM; k0 += BK6) {
        int row = r0 + ar;
        float4 av = make_float4(0.f, 0.f, 0.f, 0.f);
        if (row < N_NODES)
            av = *(const float4*)&outg[(size_t)row * GDIM + k0 + ak];
        float4 bv = *(const float4*)&gat_bias[k0 + ak];
        av.x = fmaxf(av.x + bv.x, 0.f);
        av.y = fmaxf(av.y + bv.y, 0.f);
        av.z = fmaxf(av.z + bv.z, 0.f);
        av.w = fmaxf(av.w + bv.w, 0.f);
        sA[ak + 0][ar] = av.x;
        sA[ak + 1][ar] = av.y;
        sA[ak + 2][ar] = av.z;
        sA[ak + 3][ar] = av.w;
#pragma unroll
        for (int p = 0; p < 2; p++) {
            int kk = (tid >> 5) + p * 8;
            int c = (tid & 31) * 4;
            *(float4*)&sW[kk][c] = *(const float4*)&fc_w[(size_t)(k0 + kk) * FINAL + c];
        }
        __syncthreads();
#pragma unroll
        for (int kk = 0; kk < BK6; kk++) {
            float4 w = *(const float4*)&sW[kk][tcol];
            float4 a0 = *(const float4*)&sA[kk][trow];
            float4 a1 = *(const float4*)&sA[kk][trow + 4];
            float a[8] = {a0.x, a0.y, a0.z, a0.w, a1.x, a1.y, a1.z, a1.w};
#pragma unroll
            for (int r = 0; r < 8; r++) {
                acc[r][0] += a[r] * w.x;
                acc[r][1] += a[r] * w.y;
                acc[r][2] += a[r] * w.z;
                acc[r][3] += a[r] * w.w;
            }
        }
        __syncthreads();
    }

    float4 fb = *(const float4*)&fc_b[tcol];
#pragma unroll
    for (int r = 0; r < 8; r++) {
        int row = r0 + trow + r;
        if (row < N_NODES) {
            *(float4*)&y[(size_t)row * FINAL + tcol] =
                make_float4(acc[r][0] + fb.x, acc[r][1] + fb.y,
                            acc[r][2] + fb.z, acc[r][3] + fb.w);
        }
    }
}

extern "C" void kernel_launch(void* const* d_in, const int* in_sizes, int n_in,
                              void* d_out, int out_size, void* d_ws, size_t ws_size,
                              hipStream_t stream)
{
    const float* x        = (const float*)d_in[0];
    const int*   ei       = (const int*)d_in[1];
    const float* ea       = (const float*)d_in[2];
    const float* ecc_root = (const float*)d_in[3];
    const float* ecc_bias = (const float*)d_in[4];
    const float* mlp_w    = (const float*)d_in[5];
    const float* mlp_b    = (const float*)d_in[6];
    const float* gat_lin  = (const float*)d_in[7];
    const float* att_src  = (const float*)d_in[8];
    const float* att_dst  = (const float*)d_in[9];
    const float* gat_bias = (const float*)d_in[10];
    const float* fc_w     = (const float*)d_in[11];
    const float* fc_b     = (const float*)d_in[12];
    float* y = (float*)d_out;

    const int* src = ei;
    const int* dst = ei + N_EDGES;

    // workspace layout
    float* ws = (float*)d_ws;
    float* msgbuf = ws;                                    // E*16 floats (51.2 MB)
    float* g      = msgbuf + (size_t)N_EDGES * OUT_C;      // N*256 floats (51.2 MB)
    float* asrc   = g + (size_t)N_NODES * GDIM;            // N*4
    float* adst   = asrc + (size_t)N_NODES * HEADS;        // N*4
    int*   cnt      = (int*)(adst + (size_t)N_NODES * HEADS); // N
    int*   offs     = cnt + N_NODES;                       // N+1
    int*   cursor   = offs + N_NODES + 1;                  // N
    int*   part     = cursor + N_NODES;                    // 256
    int*   partscan = part + 256;                          // 256
    int*   eidx     = partscan + 256;                      // E
    float* outg     = msgbuf;  // alias: msgbuf dead after k2b_node

    hipMemsetAsync(cnt, 0, sizeof(int) * N_NODES, stream);

    int eb = (N_EDGES + 255) / 256;
    k_hist   <<<eb, 256, 0, stream>>>(dst, cnt);
    k_part   <<<NBLK, 256, 0, stream>>>(cnt, part);
    k_scan1  <<<1, 256, 0, stream>>>(part, partscan);
    k_add    <<<NBLK, 256, 0, stream>>>(cnt, partscan, offs, cursor);
    k_scatter<<<eb, 256, 0, stream>>>(dst, cursor, eidx);

    k1b_msg  <<<eb, 256, 0, stream>>>(x, ea, src, mlp_w, mlp_b, msgbuf);
    k2b_node <<<(N_NODES + 3) / 4, 256, 0, stream>>>(x, msgbuf, offs, eidx,
                                                     ecc_root, ecc_bias, gat_lin,
                                                     att_src, att_dst, g, asrc, adst);
    k_gat    <<<N_NODES, 256, 0, stream>>>(offs, eidx, src, asrc, adst, g, outg);
    k6_final <<<(N_NODES + BM - 1) / BM, 256, 0, stream>>>(outg, gat_bias, fc_w, fc_b, y);
}

// Round 3
// 399.375 us; speedup vs baseline: 4.5455x; 1.2167x over previous
//
#include <hip/hip_runtime.h>

#define N_NODES 50000
#define N_EDGES 800000
#define IN_C 8
#define OUT_C 16
#define EDGE_F 8
#define HEADS 4
#define HID 64
#define GDIM (HEADS*HID)   // 256
#define FINAL 128
#define NEG_SLOPE 0.2f
#define NBLK 196           // ceil(N_NODES/256)

__device__ __forceinline__ int clampn(int v) {
    return v < 0 ? 0 : (v >= N_NODES ? N_NODES - 1 : v);
}
__device__ __forceinline__ unsigned short f32_to_bf16(float f) {
    unsigned u = __float_as_uint(f);
    unsigned r = (u + 0x7fffu + ((u >> 16) & 1u)) >> 16;   // RNE
    return (unsigned short)r;
}
__device__ __forceinline__ float bf16_to_f32(unsigned short h) {
    return __uint_as_float(((unsigned)h) << 16);
}

// ---------- CSR build ----------
// k_hist: histogram AND per-edge within-node rank (atomic return value)
__global__ __launch_bounds__(256) void k_hist(const int* __restrict__ dst,
                                              int* __restrict__ cnt,
                                              int* __restrict__ rnk)
{
    int e = blockIdx.x * 256 + threadIdx.x;
    if (e >= N_EDGES) return;
    rnk[e] = atomicAdd(&cnt[clampn(dst[e])], 1);
}

__global__ __launch_bounds__(256) void k_part(const int* __restrict__ cnt,
                                              int* __restrict__ part)
{
    int i = blockIdx.x * 256 + threadIdx.x;
    int v = (i < N_NODES) ? cnt[i] : 0;
#pragma unroll
    for (int off = 32; off; off >>= 1) v += __shfl_down(v, off);
    __shared__ int ws[4];
    if ((threadIdx.x & 63) == 0) ws[threadIdx.x >> 6] = v;
    __syncthreads();
    if (threadIdx.x == 0) part[blockIdx.x] = ws[0] + ws[1] + ws[2] + ws[3];
}

__global__ __launch_bounds__(256) void k_scan1(const int* __restrict__ part,
                                               int* __restrict__ partscan)
{
    int t = threadIdx.x;
    int v = (t < NBLK) ? part[t] : 0;
    int lane = t & 63, wid = t >> 6;
    int incl = v;
#pragma unroll
    for (int off = 1; off < 64; off <<= 1) {
        int u = __shfl_up(incl, off);
        if (lane >= off) incl += u;
    }
    __shared__ int wsum[4];
    if (lane == 63) wsum[wid] = incl;
    __syncthreads();
    int add = 0;
    for (int w = 0; w < wid; w++) add += wsum[w];
    partscan[t] = incl - v + add;   // exclusive
}

__global__ __launch_bounds__(256) void k_add(const int* __restrict__ cnt,
                                             const int* __restrict__ partscan,
                                             int* __restrict__ offs)
{
    int i = blockIdx.x * 256 + threadIdx.x;
    int v = (i < N_NODES) ? cnt[i] : 0;
    int lane = threadIdx.x & 63, wid = threadIdx.x >> 6;
    int incl = v;
#pragma unroll
    for (int off = 1; off < 64; off <<= 1) {
        int u = __shfl_up(incl, off);
        if (lane >= off) incl += u;
    }
    __shared__ int wsum[4];
    if (lane == 63) wsum[wid] = incl;
    __syncthreads();
    int add = partscan[blockIdx.x];
    for (int w = 0; w < wid; w++) add += wsum[w];
    if (i < N_NODES) offs[i] = incl - v + add;
    if (i == 0) offs[N_NODES] = N_EDGES;
}

// ---------- K1b: per-edge NNConv message, written at CSR position (fused scatter) ----------
__global__ __launch_bounds__(256) void k1b_msg(
    const float* __restrict__ x, const float* __restrict__ ea,
    const int* __restrict__ src, const int* __restrict__ dst,
    const int* __restrict__ rnk, const int* __restrict__ offs,
    const float* __restrict__ mlp_w, const float* __restrict__ mlp_b,
    float* __restrict__ msgbuf, int* __restrict__ src_csr)
{
    __shared__ float smw[EDGE_F * IN_C * OUT_C];  // 1024
    __shared__ float smb[IN_C * OUT_C];           // 128
    for (int i = threadIdx.x; i < EDGE_F * IN_C * OUT_C; i += 256) smw[i] = mlp_w[i];
    for (int i = threadIdx.x; i < IN_C * OUT_C; i += 256) smb[i] = mlp_b[i];
    __syncthreads();

    int e = blockIdx.x * 256 + threadIdx.x;
    if (e >= N_EDGES) return;
    int s = clampn(src[e]);
    int d = clampn(dst[e]);
    int p = offs[d] + rnk[e];          // CSR position
    src_csr[p] = s;

    float xe[IN_C], att[EDGE_F];
#pragma unroll
    for (int i = 0; i < IN_C; i++) xe[i] = x[s * IN_C + i];
#pragma unroll
    for (int f = 0; f < EDGE_F; f++) att[f] = ea[e * EDGE_F + f];

    float msg[OUT_C];
#pragma unroll
    for (int o = 0; o < OUT_C; o++) msg[o] = 0.f;
#pragma unroll
    for (int i = 0; i < IN_C; i++) {
#pragma unroll
        for (int o = 0; o < OUT_C; o++) {
            float w = smb[i * OUT_C + o];
#pragma unroll
            for (int f = 0; f < EDGE_F; f++)
                w += att[f] * smw[f * (IN_C * OUT_C) + i * OUT_C + o];
            msg[o] += xe[i] * w;
        }
    }
#pragma unroll
    for (int o = 0; o < OUT_C; o += 4)
        *(float4*)&msgbuf[(size_t)p * OUT_C + o] =
            make_float4(msg[o], msg[o+1], msg[o+2], msg[o+3]);
}

// ---------- K2b: per-node (one wave): agg (contiguous CSR reads) + h + g(bf16) + logits ----------
__global__ __launch_bounds__(256) void k2b_node(
    const float* __restrict__ x, const float* __restrict__ msgbuf,
    const int* __restrict__ offs,
    const float* __restrict__ ecc_root, const float* __restrict__ ecc_bias,
    const float* __restrict__ gat_lin,
    const float* __restrict__ att_src_w, const float* __restrict__ att_dst_w,
    unsigned short* __restrict__ g_bf, float* __restrict__ asrc, float* __restrict__ adst)
{
    int wid = threadIdx.x >> 6, lane = threadIdx.x & 63;
    int n = blockIdx.x * 4 + wid;
    if (n >= N_NODES) return;

    int o = lane & 15, q = lane >> 4;     // 4 edge-groups x 16 outputs
    int beg = offs[n], end = offs[n + 1];

    float aggv = 0.f;
    for (int j = beg + q; j < end; j += 4)
        aggv += msgbuf[(size_t)j * OUT_C + o];   // fully sequential per wave
    aggv += __shfl_down(aggv, 32);
    aggv += __shfl_down(aggv, 16);        // lanes 0..15 hold per-o totals

    float hv = 0.f;
    if (lane < 16) {
        float v = ecc_bias[o] + aggv;
#pragma unroll
        for (int i = 0; i < IN_C; i++) v += x[n * IN_C + i] * ecc_root[i * OUT_C + o];
        hv = fmaxf(v, 0.f);
    }

    float gv[4] = {0.f, 0.f, 0.f, 0.f};
#pragma unroll
    for (int k = 0; k < OUT_C; k++) {
        float hk = __shfl(hv, k);
#pragma unroll
        for (int j = 0; j < 4; j++)
            gv[j] += hk * gat_lin[k * GDIM + j * 64 + lane];
    }
#pragma unroll
    for (int j = 0; j < 4; j++)
        g_bf[(size_t)n * GDIM + j * 64 + lane] = f32_to_bf16(gv[j]);

    float vs[4], vd[4];
#pragma unroll
    for (int j = 0; j < 4; j++) {
        vs[j] = gv[j] * att_src_w[j * 64 + lane];
        vd[j] = gv[j] * att_dst_w[j * 64 + lane];
    }
#pragma unroll
    for (int off = 32; off; off >>= 1) {
#pragma unroll
        for (int j = 0; j < 4; j++) {
            vs[j] += __shfl_down(vs[j], off);
            vd[j] += __shfl_down(vd[j], off);
        }
    }
    if (lane == 0) {
#pragma unroll
        for (int j = 0; j < 4; j++) {
            asrc[n * HEADS + j] = vs[j];
            adst[n * HEADS + j] = vd[j];
        }
    }
}

// ---------- K_gat: single-pass fused softmax + aggregate (block per node, no max) ----------
// Softmax is shift-invariant; logits are bounded (|a|<~10 by weight-scale), exp() safe in fp32.
__global__ __launch_bounds__(256) void k_gat(
    const int* __restrict__ offs, const int* __restrict__ src_csr,
    const float* __restrict__ asrc, const float* __restrict__ adst,
    const unsigned short* __restrict__ g_bf, float* __restrict__ outg)
{
    int n = blockIdx.x;
    int t = threadIdx.x;
    int beg = offs[n], deg = offs[n + 1] - beg;

    __shared__ float s_adst[HEADS];
    __shared__ float s_al[64 * HEADS];
    __shared__ int   s_sid[64];
    __shared__ float s_wsum[4][HEADS];
    __shared__ float s_den[HEADS];

    int j = t >> 2, h = t & 3;    // 64 edge-workers x 4 heads
    int head = t >> 6;            // accumulation role: dim t, head = t/64
    if (t < HEADS) s_adst[t] = adst[n * HEADS + t];
    __syncthreads();

    float acc = 0.f, denp = 0.f;
    for (int c0 = 0; c0 < deg; c0 += 64) {
        int nc = min(64, deg - c0);
        if (j < nc) {
            int s = src_csr[beg + c0 + j];
            if (h == 0) s_sid[j] = s;
            float v = asrc[s * HEADS + h] + s_adst[h];
            v = v > 0.f ? v : NEG_SLOPE * v;
            float p = __expf(v);
            s_al[j * HEADS + h] = p;
            denp += p;
        }
        __syncthreads();
        for (int k = 0; k < nc; k++) {
            int s = s_sid[k];
            acc += s_al[k * HEADS + head] *
                   bf16_to_f32(g_bf[(size_t)s * GDIM + t]);
        }
        __syncthreads();
    }
#pragma unroll
    for (int mask = 4; mask < 64; mask <<= 1) denp += __shfl_xor(denp, mask);
    if ((t & 63) < 4) s_wsum[t >> 6][t & 3] = denp;
    __syncthreads();
    if (t < HEADS)
        s_den[t] = s_wsum[0][t] + s_wsum[1][t] + s_wsum[2][t] + s_wsum[3][t];
    __syncthreads();

    outg[(size_t)n * GDIM + t] = acc / (s_den[head] + 1e-16f);
}

// ---------- K6: y = relu(outg + gat_bias) @ fc_w + fc_b ----------
#define BM 64
#define BK6 16
__global__ __launch_bounds__(256) void k6_final(
    const float* __restrict__ outg, const float* __restrict__ gat_bias,
    const float* __restrict__ fc_w, const float* __restrict__ fc_b,
    float* __restrict__ y)
{
    __shared__ float sA[BK6][BM + 4];
    __shared__ float sW[BK6][FINAL];
    int tid = threadIdx.x;
    int r0 = blockIdx.x * BM;
    int tcol = (tid & 31) * 4;
    int trow = (tid >> 5) * 8;

    float acc[8][4];
#pragma unroll
    for (int r = 0; r < 8; r++)
#pragma unroll
        for (int c = 0; c < 4; c++) acc[r][c] = 0.f;

    int ar = tid >> 2;
    int ak = (tid & 3) * 4;

    for (int k0 = 0; k0 < GDIM; k0 += BK6) {
        int row = r0 + ar;
        float4 av = make_float4(0.f, 0.f, 0.f, 0.f);
        if (row < N_NODES)
            av = *(const float4*)&outg[(size_t)row * GDIM + k0 + ak];
        float4 bv = *(const float4*)&gat_bias[k0 + ak];
        av.x = fmaxf(av.x + bv.x, 0.f);
        av.y = fmaxf(av.y + bv.y, 0.f);
        av.z = fmaxf(av.z + bv.z, 0.f);
        av.w = fmaxf(av.w + bv.w, 0.f);
        sA[ak + 0][ar] = av.x;
        sA[ak + 1][ar] = av.y;
        sA[ak + 2][ar] = av.z;
        sA[ak + 3][ar] = av.w;
#pragma unroll
        for (int p = 0; p < 2; p++) {
            int kk = (tid >> 5) + p * 8;
            int c = (tid & 31) * 4;
            *(float4*)&sW[kk][c] = *(const float4*)&fc_w[(size_t)(k0 + kk) * FINAL + c];
        }
        __syncthreads();
#pragma unroll
        for (int kk = 0; kk < BK6; kk++) {
            float4 w = *(const float4*)&sW[kk][tcol];
            float4 a0 = *(const float4*)&sA[kk][trow];
            float4 a1 = *(const float4*)&sA[kk][trow + 4];
            float a[8] = {a0.x, a0.y, a0.z, a0.w, a1.x, a1.y, a1.z, a1.w};
#pragma unroll
            for (int r = 0; r < 8; r++) {
                acc[r][0] += a[r] * w.x;
                acc[r][1] += a[r] * w.y;
                acc[r][2] += a[r] * w.z;
                acc[r][3] += a[r] * w.w;
            }
        }
        __syncthreads();
    }

    float4 fb = *(const float4*)&fc_b[tcol];
#pragma unroll
    for (int r = 0; r < 8; r++) {
        int row = r0 + trow + r;
        if (row < N_NODES) {
            *(float4*)&y[(size_t)row * FINAL + tcol] =
                make_float4(acc[r][0] + fb.x, acc[r][1] + fb.y,
                            acc[r][2] + fb.z, acc[r][3] + fb.w);
        }
    }
}

extern "C" void kernel_launch(void* const* d_in, const int* in_sizes, int n_in,
                              void* d_out, int out_size, void* d_ws, size_t ws_size,
                              hipStream_t stream)
{
    const float* x        = (const float*)d_in[0];
    const int*   ei       = (const int*)d_in[1];
    const float* ea       = (const float*)d_in[2];
    const float* ecc_root = (const float*)d_in[3];
    const float* ecc_bias = (const float*)d_in[4];
    const float* mlp_w    = (const float*)d_in[5];
    const float* mlp_b    = (const float*)d_in[6];
    const float* gat_lin  = (const float*)d_in[7];
    const float* att_src  = (const float*)d_in[8];
    const float* att_dst  = (const float*)d_in[9];
    const float* gat_bias = (const float*)d_in[10];
    const float* fc_w     = (const float*)d_in[11];
    const float* fc_b     = (const float*)d_in[12];
    float* y = (float*)d_out;

    const int* src = ei;
    const int* dst = ei + N_EDGES;

    // workspace layout
    float* ws = (float*)d_ws;
    float*          msgbuf = ws;                                  // E*16 floats (51.2 MB)
    unsigned short* g_bf   = (unsigned short*)(msgbuf + (size_t)N_EDGES * OUT_C); // N*256 bf16 (25.6 MB)
    float* asrc   = (float*)(g_bf + (size_t)N_NODES * GDIM);      // N*4
    float* adst   = asrc + (size_t)N_NODES * HEADS;               // N*4
    int*   cnt      = (int*)(adst + (size_t)N_NODES * HEADS);     // N
    int*   offs     = cnt + N_NODES;                              // N+1
    int*   part     = offs + N_NODES + 1;                         // 256
    int*   partscan = part + 256;                                 // 256
    int*   rnk      = partscan + 256;                             // E
    int*   src_csr  = rnk + N_EDGES;                              // E
    float* outg     = msgbuf;  // alias: msgbuf dead after k2b_node (both 12.8M floats)

    hipMemsetAsync(cnt, 0, sizeof(int) * N_NODES, stream);

    int eb = (N_EDGES + 255) / 256;
    k_hist   <<<eb, 256, 0, stream>>>(dst, cnt, rnk);
    k_part   <<<NBLK, 256, 0, stream>>>(cnt, part);
    k_scan1  <<<1, 256, 0, stream>>>(part, partscan);
    k_add    <<<NBLK, 256, 0, stream>>>(cnt, partscan, offs);

    k1b_msg  <<<eb, 256, 0, stream>>>(x, ea, src, dst, rnk, offs, mlp_w, mlp_b,
                                      msgbuf, src_csr);
    k2b_node <<<(N_NODES + 3) / 4, 256, 0, stream>>>(x, msgbuf, offs,
                                                     ecc_root, ecc_bias, gat_lin,
                                                     att_src, att_dst, g_bf, asrc, adst);
    k_gat    <<<N_NODES, 256, 0, stream>>>(offs, src_csr, asrc, adst, g_bf, outg);
    k6_final <<<(N_NODES + BM - 1) / BM, 256, 0, stream>>>(outg, gat_bias, fc_w, fc_b, y);
}

// Round 4
// 399.223 us; speedup vs baseline: 4.5473x; 1.0004x over previous
//
#include <hip/hip_runtime.h>

#define N_NODES 50000
#define N_EDGES 800000
#define IN_C 8
#define OUT_C 16
#define EDGE_F 8
#define HEADS 4
#define HID 64
#define GDIM (HEADS*HID)   // 256
#define FINAL 128
#define NEG_SLOPE 0.2f
#define NBLK 196           // ceil(N_NODES/256)

__device__ __forceinline__ int clampn(int v) {
    return v < 0 ? 0 : (v >= N_NODES ? N_NODES - 1 : v);
}
__device__ __forceinline__ unsigned short f32_to_bf16(float f) {
    unsigned u = __float_as_uint(f);
    unsigned r = (u + 0x7fffu + ((u >> 16) & 1u)) >> 16;   // RNE
    return (unsigned short)r;
}
__device__ __forceinline__ float bf16_to_f32(unsigned short h) {
    return __uint_as_float(((unsigned)h) << 16);
}
__device__ __forceinline__ float bf16lo(unsigned u) { return __uint_as_float(u << 16); }
__device__ __forceinline__ float bf16hi(unsigned u) { return __uint_as_float(u & 0xffff0000u); }

// ---------- CSR build ----------
__global__ __launch_bounds__(256) void k_hist(const int* __restrict__ dst,
                                              int* __restrict__ cnt,
                                              int* __restrict__ rnk)
{
    int e = blockIdx.x * 256 + threadIdx.x;
    if (e >= N_EDGES) return;
    rnk[e] = atomicAdd(&cnt[clampn(dst[e])], 1);
}

__global__ __launch_bounds__(256) void k_part(const int* __restrict__ cnt,
                                              int* __restrict__ part)
{
    int i = blockIdx.x * 256 + threadIdx.x;
    int v = (i < N_NODES) ? cnt[i] : 0;
#pragma unroll
    for (int off = 32; off; off >>= 1) v += __shfl_down(v, off);
    __shared__ int ws[4];
    if ((threadIdx.x & 63) == 0) ws[threadIdx.x >> 6] = v;
    __syncthreads();
    if (threadIdx.x == 0) part[blockIdx.x] = ws[0] + ws[1] + ws[2] + ws[3];
}

__global__ __launch_bounds__(256) void k_scan1(const int* __restrict__ part,
                                               int* __restrict__ partscan)
{
    int t = threadIdx.x;
    int v = (t < NBLK) ? part[t] : 0;
    int lane = t & 63, wid = t >> 6;
    int incl = v;
#pragma unroll
    for (int off = 1; off < 64; off <<= 1) {
        int u = __shfl_up(incl, off);
        if (lane >= off) incl += u;
    }
    __shared__ int wsum[4];
    if (lane == 63) wsum[wid] = incl;
    __syncthreads();
    int add = 0;
    for (int w = 0; w < wid; w++) add += wsum[w];
    partscan[t] = incl - v + add;   // exclusive
}

__global__ __launch_bounds__(256) void k_add(const int* __restrict__ cnt,
                                             const int* __restrict__ partscan,
                                             int* __restrict__ offs)
{
    int i = blockIdx.x * 256 + threadIdx.x;
    int v = (i < N_NODES) ? cnt[i] : 0;
    int lane = threadIdx.x & 63, wid = threadIdx.x >> 6;
    int incl = v;
#pragma unroll
    for (int off = 1; off < 64; off <<= 1) {
        int u = __shfl_up(incl, off);
        if (lane >= off) incl += u;
    }
    __shared__ int wsum[4];
    if (lane == 63) wsum[wid] = incl;
    __syncthreads();
    int add = partscan[blockIdx.x];
    for (int w = 0; w < wid; w++) add += wsum[w];
    if (i < N_NODES) offs[i] = incl - v + add;
    if (i == 0) offs[N_NODES] = N_EDGES;
}

// ---------- K1b: per-edge NNConv message (bf16), written at CSR position ----------
__global__ __launch_bounds__(256) void k1b_msg(
    const float* __restrict__ x, const float* __restrict__ ea,
    const int* __restrict__ src, const int* __restrict__ dst,
    const int* __restrict__ rnk, const int* __restrict__ offs,
    const float* __restrict__ mlp_w, const float* __restrict__ mlp_b,
    unsigned short* __restrict__ msgbuf, int* __restrict__ src_csr)
{
    __shared__ float smw[EDGE_F * IN_C * OUT_C];  // 1024
    __shared__ float smb[IN_C * OUT_C];           // 128
    for (int i = threadIdx.x; i < EDGE_F * IN_C * OUT_C; i += 256) smw[i] = mlp_w[i];
    for (int i = threadIdx.x; i < IN_C * OUT_C; i += 256) smb[i] = mlp_b[i];
    __syncthreads();

    int e = blockIdx.x * 256 + threadIdx.x;
    if (e >= N_EDGES) return;
    int s = clampn(src[e]);
    int d = clampn(dst[e]);
    int p = offs[d] + rnk[e];          // CSR position
    src_csr[p] = s;

    float xe[IN_C], att[EDGE_F];
#pragma unroll
    for (int i = 0; i < IN_C; i++) xe[i] = x[s * IN_C + i];
#pragma unroll
    for (int f = 0; f < EDGE_F; f++) att[f] = ea[e * EDGE_F + f];

    float msg[OUT_C];
#pragma unroll
    for (int o = 0; o < OUT_C; o++) msg[o] = 0.f;
#pragma unroll
    for (int i = 0; i < IN_C; i++) {
#pragma unroll
        for (int o = 0; o < OUT_C; o++) {
            float w = smb[i * OUT_C + o];
#pragma unroll
            for (int f = 0; f < EDGE_F; f++)
                w += att[f] * smw[f * (IN_C * OUT_C) + i * OUT_C + o];
            msg[o] += xe[i] * w;
        }
    }
    unsigned pk[8];
#pragma unroll
    for (int o = 0; o < OUT_C; o += 2)
        pk[o >> 1] = (unsigned)f32_to_bf16(msg[o]) |
                     ((unsigned)f32_to_bf16(msg[o + 1]) << 16);
    *(uint4*)&msgbuf[(size_t)p * OUT_C]     = make_uint4(pk[0], pk[1], pk[2], pk[3]);
    *(uint4*)&msgbuf[(size_t)p * OUT_C + 8] = make_uint4(pk[4], pk[5], pk[6], pk[7]);
}

// ---------- K2b: per-node (one wave): agg (contiguous CSR reads) + h + g(bf16) + logits ----------
__global__ __launch_bounds__(256) void k2b_node(
    const float* __restrict__ x, const unsigned short* __restrict__ msgbuf,
    const int* __restrict__ offs,
    const float* __restrict__ ecc_root, const float* __restrict__ ecc_bias,
    const float* __restrict__ gat_lin,
    const float* __restrict__ att_src_w, const float* __restrict__ att_dst_w,
    unsigned short* __restrict__ g_bf, float* __restrict__ asrc, float* __restrict__ adst)
{
    int wid = threadIdx.x >> 6, lane = threadIdx.x & 63;
    int n = blockIdx.x * 4 + wid;
    if (n >= N_NODES) return;

    int o = lane & 15, q = lane >> 4;     // 4 edge-groups x 16 outputs
    int beg = offs[n], end = offs[n + 1];

    float aggv = 0.f;
    for (int j = beg + q; j < end; j += 4)
        aggv += bf16_to_f32(msgbuf[(size_t)j * OUT_C + o]);
    aggv += __shfl_down(aggv, 32);
    aggv += __shfl_down(aggv, 16);        // lanes 0..15 hold per-o totals

    float hv = 0.f;
    if (lane < 16) {
        float v = ecc_bias[o] + aggv;
#pragma unroll
        for (int i = 0; i < IN_C; i++) v += x[n * IN_C + i] * ecc_root[i * OUT_C + o];
        hv = fmaxf(v, 0.f);
    }

    float gv[4] = {0.f, 0.f, 0.f, 0.f};
#pragma unroll
    for (int k = 0; k < OUT_C; k++) {
        float hk = __shfl(hv, k);
#pragma unroll
        for (int j = 0; j < 4; j++)
            gv[j] += hk * gat_lin[k * GDIM + j * 64 + lane];
    }
#pragma unroll
    for (int j = 0; j < 4; j++)
        g_bf[(size_t)n * GDIM + j * 64 + lane] = f32_to_bf16(gv[j]);

    float vs[4], vd[4];
#pragma unroll
    for (int j = 0; j < 4; j++) {
        vs[j] = gv[j] * att_src_w[j * 64 + lane];
        vd[j] = gv[j] * att_dst_w[j * 64 + lane];
    }
#pragma unroll
    for (int off = 32; off; off >>= 1) {
#pragma unroll
        for (int j = 0; j < 4; j++) {
            vs[j] += __shfl_down(vs[j], off);
            vd[j] += __shfl_down(vd[j], off);
        }
    }
    if (lane == 0) {
#pragma unroll
        for (int j = 0; j < 4; j++) {
            asrc[n * HEADS + j] = vs[j];
            adst[n * HEADS + j] = vd[j];
        }
    }
}

// ---------- K_gat: single-pass fused softmax + aggregate ----------
// 8 thread-groups of 32 lanes; each group owns one edge per step, each lane
// loads 16 B (8 bf16 dims) -> 8 independent uint4 loads in flight.
__global__ __launch_bounds__(256) void k_gat(
    const int* __restrict__ offs, const int* __restrict__ src_csr,
    const float* __restrict__ asrc, const float* __restrict__ adst,
    const unsigned short* __restrict__ g_bf, unsigned short* __restrict__ outg)
{
    int n = blockIdx.x;
    int t = threadIdx.x;
    int beg = offs[n], deg = offs[n + 1] - beg;

    __shared__ float s_adst[HEADS];
    __shared__ float s_al[64 * HEADS];    // alpha-unnormalized per chunk
    __shared__ int   s_sid[64];
    __shared__ float s_wsum[4][HEADS];
    __shared__ float s_den[HEADS];
    __shared__ float s_acc[8][GDIM];      // 8 KB: per-group partial sums

    int j = t >> 2, h = t & 3;            // exp-phase: 64 edge-workers x 4 heads
    int lane32 = t & 31, grp = t >> 5;    // accum-phase: 8 groups x 32 lanes
    int myhead = lane32 >> 3;             // dims lane32*8..+7 are all in this head

    if (t < HEADS) s_adst[t] = adst[n * HEADS + t];
    __syncthreads();

    float acc[8];
#pragma unroll
    for (int k = 0; k < 8; k++) acc[k] = 0.f;
    float denp = 0.f;

    for (int c0 = 0; c0 < deg; c0 += 64) {
        int nc = min(64, deg - c0);
        if (j < nc) {
            int s = src_csr[beg + c0 + j];
            if (h == 0) s_sid[j] = s;
            float v = asrc[s * HEADS + h] + s_adst[h];
            v = v > 0.f ? v : NEG_SLOPE * v;
            float p = __expf(v);
            s_al[j * HEADS + h] = p;
            denp += p;
        }
        __syncthreads();
        for (int k8 = 0; k8 < nc; k8 += 8) {
            int e = k8 + grp;
            if (e < nc) {
                int s = s_sid[e];
                float a = s_al[e * HEADS + myhead];
                uint4 gv = *(const uint4*)&g_bf[(size_t)s * GDIM + lane32 * 8];
                acc[0] += a * bf16lo(gv.x);
                acc[1] += a * bf16hi(gv.x);
                acc[2] += a * bf16lo(gv.y);
                acc[3] += a * bf16hi(gv.y);
                acc[4] += a * bf16lo(gv.z);
                acc[5] += a * bf16hi(gv.z);
                acc[6] += a * bf16lo(gv.w);
                acc[7] += a * bf16hi(gv.w);
            }
        }
        __syncthreads();
    }

    // denom: reduce over j within wave (keep h), then across 4 waves
#pragma unroll
    for (int mask = 4; mask < 64; mask <<= 1) denp += __shfl_xor(denp, mask);
    if ((t & 63) < 4) s_wsum[t >> 6][t & 3] = denp;
    // partial accumulators -> LDS
#pragma unroll
    for (int k = 0; k < 8; k++) s_acc[grp][lane32 * 8 + k] = acc[k];
    __syncthreads();
    if (t < HEADS)
        s_den[t] = s_wsum[0][t] + s_wsum[1][t] + s_wsum[2][t] + s_wsum[3][t];
    __syncthreads();

    float v = 0.f;
#pragma unroll
    for (int gIdx = 0; gIdx < 8; gIdx++) v += s_acc[gIdx][t];
    int head = t >> 6;
    outg[(size_t)n * GDIM + t] = f32_to_bf16(v / (s_den[head] + 1e-16f));
}

// ---------- K6: y = relu(outg + gat_bias) @ fc_w + fc_b ----------
#define BM 64
#define BK6 16
__global__ __launch_bounds__(256) void k6_final(
    const unsigned short* __restrict__ outg, const float* __restrict__ gat_bias,
    const float* __restrict__ fc_w, const float* __restrict__ fc_b,
    float* __restrict__ y)
{
    __shared__ float sA[BK6][BM + 4];
    __shared__ float sW[BK6][FINAL];
    int tid = threadIdx.x;
    int r0 = blockIdx.x * BM;
    int tcol = (tid & 31) * 4;
    int trow = (tid >> 5) * 8;

    float acc[8][4];
#pragma unroll
    for (int r = 0; r < 8; r++)
#pragma unroll
        for (int c = 0; c < 4; c++) acc[r][c] = 0.f;

    int ar = tid >> 2;
    int ak = (tid & 3) * 4;

    for (int k0 = 0; k0 < GDIM; k0 += BK6) {
        int row = r0 + ar;
        float4 av = make_float4(0.f, 0.f, 0.f, 0.f);
        if (row < N_NODES) {
            uint2 raw = *(const uint2*)&outg[(size_t)row * GDIM + k0 + ak];
            av = make_float4(bf16lo(raw.x), bf16hi(raw.x), bf16lo(raw.y), bf16hi(raw.y));
        }
        float4 bv = *(const float4*)&gat_bias[k0 + ak];
        av.x = fmaxf(av.x + bv.x, 0.f);
        av.y = fmaxf(av.y + bv.y, 0.f);
        av.z = fmaxf(av.z + bv.z, 0.f);
        av.w = fmaxf(av.w + bv.w, 0.f);
        sA[ak + 0][ar] = av.x;
        sA[ak + 1][ar] = av.y;
        sA[ak + 2][ar] = av.z;
        sA[ak + 3][ar] = av.w;
#pragma unroll
        for (int p = 0; p < 2; p++) {
            int kk = (tid >> 5) + p * 8;
            int c = (tid & 31) * 4;
            *(float4*)&sW[kk][c] = *(const float4*)&fc_w[(size_t)(k0 + kk) * FINAL + c];
        }
        __syncthreads();
#pragma unroll
        for (int kk = 0; kk < BK6; kk++) {
            float4 w = *(const float4*)&sW[kk][tcol];
            float4 a0 = *(const float4*)&sA[kk][trow];
            float4 a1 = *(const float4*)&sA[kk][trow + 4];
            float a[8] = {a0.x, a0.y, a0.z, a0.w, a1.x, a1.y, a1.z, a1.w};
#pragma unroll
            for (int r = 0; r < 8; r++) {
                acc[r][0] += a[r] * w.x;
                acc[r][1] += a[r] * w.y;
                acc[r][2] += a[r] * w.z;
                acc[r][3] += a[r] * w.w;
            }
        }
        __syncthreads();
    }

    float4 fb = *(const float4*)&fc_b[tcol];
#pragma unroll
    for (int r = 0; r < 8; r++) {
        int row = r0 + trow + r;
        if (row < N_NODES) {
            *(float4*)&y[(size_t)row * FINAL + tcol] =
                make_float4(acc[r][0] + fb.x, acc[r][1] + fb.y,
                            acc[r][2] + fb.z, acc[r][3] + fb.w);
        }
    }
}

extern "C" void kernel_launch(void* const* d_in, const int* in_sizes, int n_in,
                              void* d_out, int out_size, void* d_ws, size_t ws_size,
                              hipStream_t stream)
{
    const float* x        = (const float*)d_in[0];
    const int*   ei       = (const int*)d_in[1];
    const float* ea       = (const float*)d_in[2];
    const float* ecc_root = (const float*)d_in[3];
    const float* ecc_bias = (const float*)d_in[4];
    const float* mlp_w    = (const float*)d_in[5];
    const float* mlp_b    = (const float*)d_in[6];
    const float* gat_lin  = (const float*)d_in[7];
    const float* att_src  = (const float*)d_in[8];
    const float* att_dst  = (const float*)d_in[9];
    const float* gat_bias = (const float*)d_in[10];
    const float* fc_w     = (const float*)d_in[11];
    const float* fc_b     = (const float*)d_in[12];
    float* y = (float*)d_out;

    const int* src = ei;
    const int* dst = ei + N_EDGES;

    // workspace layout
    unsigned short* msgbuf = (unsigned short*)d_ws;                       // E*16 bf16 (25.6 MB)
    unsigned short* g_bf   = msgbuf + (size_t)N_EDGES * OUT_C;            // N*256 bf16 (25.6 MB)
    float* asrc   = (float*)(g_bf + (size_t)N_NODES * GDIM);              // N*4
    float* adst   = asrc + (size_t)N_NODES * HEADS;                       // N*4
    int*   cnt      = (int*)(adst + (size_t)N_NODES * HEADS);             // N
    int*   offs     = cnt + N_NODES;                                      // N+1
    int*   part     = offs + N_NODES + 1;                                 // 256
    int*   partscan = part + 256;                                         // 256
    int*   rnk      = partscan + 256;                                     // E
    int*   src_csr  = rnk + N_EDGES;                                      // E
    unsigned short* outg = msgbuf;  // alias: msgbuf dead after k2b_node (same size)

    hipMemsetAsync(cnt, 0, sizeof(int) * N_NODES, stream);

    int eb = (N_EDGES + 255) / 256;
    k_hist   <<<eb, 256, 0, stream>>>(dst, cnt, rnk);
    k_part   <<<NBLK, 256, 0, stream>>>(cnt, part);
    k_scan1  <<<1, 256, 0, stream>>>(part, partscan);
    k_add    <<<NBLK, 256, 0, stream>>>(cnt, partscan, offs);

    k1b_msg  <<<eb, 256, 0, stream>>>(x, ea, src, dst, rnk, offs, mlp_w, mlp_b,
                                      msgbuf, src_csr);
    k2b_node <<<(N_NODES + 3) / 4, 256, 0, stream>>>(x, msgbuf, offs,
                                                     ecc_root, ecc_bias, gat_lin,
                                                     att_src, att_dst, g_bf, asrc, adst);
    k_gat    <<<N_NODES, 256, 0, stream>>>(offs, src_csr, asrc, adst, g_bf, outg);
    k6_final <<<(N_NODES + BM - 1) / BM, 256, 0, stream>>>(outg, gat_bias, fc_w, fc_b, y);
}

// Round 5
// 397.263 us; speedup vs baseline: 4.5697x; 1.0049x over previous
//
#include <hip/hip_runtime.h>

#define N_NODES 50000
#define N_EDGES 800000
#define IN_C 8
#define OUT_C 16
#define EDGE_F 8
#define HEADS 4
#define HID 64
#define GDIM (HEADS*HID)   // 256
#define FINAL 128
#define NEG_SLOPE 0.2f
#define NBLK 196           // ceil(N_NODES/256)

__device__ __forceinline__ int clampn(int v) {
    return v < 0 ? 0 : (v >= N_NODES ? N_NODES - 1 : v);
}
__device__ __forceinline__ unsigned short f32_to_bf16(float f) {
    unsigned u = __float_as_uint(f);
    unsigned r = (u + 0x7fffu + ((u >> 16) & 1u)) >> 16;   // RNE
    return (unsigned short)r;
}
__device__ __forceinline__ float bf16_to_f32(unsigned short h) {
    return __uint_as_float(((unsigned)h) << 16);
}
__device__ __forceinline__ float bf16lo(unsigned u) { return __uint_as_float(u << 16); }
__device__ __forceinline__ float bf16hi(unsigned u) { return __uint_as_float(u & 0xffff0000u); }

// ---------- CSR build ----------
__global__ __launch_bounds__(256) void k_hist(const int* __restrict__ dst,
                                              int* __restrict__ cnt,
                                              int* __restrict__ rnk)
{
    int e = blockIdx.x * 256 + threadIdx.x;
    if (e >= N_EDGES) return;
    rnk[e] = atomicAdd(&cnt[clampn(dst[e])], 1);
}

__global__ __launch_bounds__(256) void k_part(const int* __restrict__ cnt,
                                              int* __restrict__ part)
{
    int i = blockIdx.x * 256 + threadIdx.x;
    int v = (i < N_NODES) ? cnt[i] : 0;
#pragma unroll
    for (int off = 32; off; off >>= 1) v += __shfl_down(v, off);
    __shared__ int ws[4];
    if ((threadIdx.x & 63) == 0) ws[threadIdx.x >> 6] = v;
    __syncthreads();
    if (threadIdx.x == 0) part[blockIdx.x] = ws[0] + ws[1] + ws[2] + ws[3];
}

__global__ __launch_bounds__(256) void k_scan1(const int* __restrict__ part,
                                               int* __restrict__ partscan)
{
    int t = threadIdx.x;
    int v = (t < NBLK) ? part[t] : 0;
    int lane = t & 63, wid = t >> 6;
    int incl = v;
#pragma unroll
    for (int off = 1; off < 64; off <<= 1) {
        int u = __shfl_up(incl, off);
        if (lane >= off) incl += u;
    }
    __shared__ int wsum[4];
    if (lane == 63) wsum[wid] = incl;
    __syncthreads();
    int add = 0;
    for (int w = 0; w < wid; w++) add += wsum[w];
    partscan[t] = incl - v + add;   // exclusive
}

__global__ __launch_bounds__(256) void k_add(const int* __restrict__ cnt,
                                             const int* __restrict__ partscan,
                                             int* __restrict__ offs)
{
    int i = blockIdx.x * 256 + threadIdx.x;
    int v = (i < N_NODES) ? cnt[i] : 0;
    int lane = threadIdx.x & 63, wid = threadIdx.x >> 6;
    int incl = v;
#pragma unroll
    for (int off = 1; off < 64; off <<= 1) {
        int u = __shfl_up(incl, off);
        if (lane >= off) incl += u;
    }
    __shared__ int wsum[4];
    if (lane == 63) wsum[wid] = incl;
    __syncthreads();
    int add = partscan[blockIdx.x];
    for (int w = 0; w < wid; w++) add += wsum[w];
    if (i < N_NODES) offs[i] = incl - v + add;
    if (i == 0) offs[N_NODES] = N_EDGES;
}

// ---------- K0y: per-node factored NNConv weights ----------
// Y[n][o][f] = sum_i x[n,i]*W[f,i,o]  (bf16, 8 f packed per uint4)
// z[n][o]    = sum_i x[n,i]*b[i,o]    (fp32)
__global__ __launch_bounds__(256) void k0_y(
    const float* __restrict__ x,
    const float* __restrict__ mlp_w, const float* __restrict__ mlp_b,
    uint4* __restrict__ Y4, float* __restrict__ z)
{
    __shared__ float smw[EDGE_F * IN_C * OUT_C];  // 1024
    __shared__ float smb[IN_C * OUT_C];           // 128
    for (int i = threadIdx.x; i < EDGE_F * IN_C * OUT_C; i += 256) smw[i] = mlp_w[i];
    for (int i = threadIdx.x; i < IN_C * OUT_C; i += 256) smb[i] = mlp_b[i];
    __syncthreads();

    int t = blockIdx.x * 256 + threadIdx.x;
    int n = t >> 4, o = t & 15;
    if (n >= N_NODES) return;

    float xv[IN_C];
#pragma unroll
    for (int i = 0; i < IN_C; i++) xv[i] = x[n * IN_C + i];

    float zf = 0.f;
#pragma unroll
    for (int i = 0; i < IN_C; i++) zf += xv[i] * smb[i * OUT_C + o];
    z[n * OUT_C + o] = zf;

    unsigned pk[4];
#pragma unroll
    for (int f2 = 0; f2 < EDGE_F; f2 += 2) {
        float y0 = 0.f, y1 = 0.f;
#pragma unroll
        for (int i = 0; i < IN_C; i++) {
            y0 += xv[i] * smw[f2 * (IN_C * OUT_C) + i * OUT_C + o];
            y1 += xv[i] * smw[(f2 + 1) * (IN_C * OUT_C) + i * OUT_C + o];
        }
        pk[f2 >> 1] = (unsigned)f32_to_bf16(y0) | ((unsigned)f32_to_bf16(y1) << 16);
    }
    Y4[(size_t)n * OUT_C + o] = make_uint4(pk[0], pk[1], pk[2], pk[3]);
}

// ---------- K_prep: place edge_attr + src into CSR order (pure data movement) ----------
__global__ __launch_bounds__(256) void k_prep(
    const int* __restrict__ src, const int* __restrict__ dst,
    const int* __restrict__ rnk, const int* __restrict__ offs,
    const float* __restrict__ ea,
    int* __restrict__ src_csr, float* __restrict__ ea_csr)
{
    int e = blockIdx.x * 256 + threadIdx.x;
    if (e >= N_EDGES) return;
    int p = offs[clampn(dst[e])] + rnk[e];
    src_csr[p] = clampn(src[e]);
    float4 a0 = *(const float4*)&ea[(size_t)e * EDGE_F];
    float4 a1 = *(const float4*)&ea[(size_t)e * EDGE_F + 4];
    *(float4*)&ea_csr[(size_t)p * EDGE_F]     = a0;
    *(float4*)&ea_csr[(size_t)p * EDGE_F + 4] = a1;
}

// ---------- K2c: fused NNConv-aggregate + node transform + attention logits ----------
// One wave per node. Lane roles: el = lane>>4 (4 edges in flight), o = lane&15.
// Per edge: msg[o] = att . Y[s,:,o] + z[s,o]; agg accumulated per lane.
__global__ __launch_bounds__(256) void k2c_node(
    const float* __restrict__ x, const uint4* __restrict__ Y4,
    const float* __restrict__ z,
    const int* __restrict__ offs, const int* __restrict__ src_csr,
    const float4* __restrict__ ea_csr4,
    const float* __restrict__ ecc_root, const float* __restrict__ ecc_bias,
    const float* __restrict__ gat_lin,
    const float* __restrict__ att_src_w, const float* __restrict__ att_dst_w,
    unsigned short* __restrict__ g_bf, float* __restrict__ asrc, float* __restrict__ adst)
{
    int wid = threadIdx.x >> 6, lane = threadIdx.x & 63;
    int n = blockIdx.x * 4 + wid;
    if (n >= N_NODES) return;

    int o = lane & 15, el = lane >> 4;
    int beg = offs[n], deg = offs[n + 1] - beg;

    float aggv = 0.f;
    for (int c0 = 0; c0 < deg; c0 += 4) {
        int j = c0 + el;
        if (j < deg) {
            int s = src_csr[beg + j];
            float4 a0 = ea_csr4[(size_t)(beg + j) * 2];       // broadcast across 16 lanes
            float4 a1 = ea_csr4[(size_t)(beg + j) * 2 + 1];
            uint4 yv = Y4[(size_t)s * OUT_C + o];             // 256 B contiguous per edge
            float m = z[s * OUT_C + o];
            m += a0.x * bf16lo(yv.x) + a0.y * bf16hi(yv.x)
               + a0.z * bf16lo(yv.y) + a0.w * bf16hi(yv.y)
               + a1.x * bf16lo(yv.z) + a1.y * bf16hi(yv.z)
               + a1.z * bf16lo(yv.w) + a1.w * bf16hi(yv.w);
            aggv += m;
        }
    }
    aggv += __shfl_down(aggv, 32);
    aggv += __shfl_down(aggv, 16);        // lanes 0..15 hold per-o totals

    float hv = 0.f;
    if (lane < 16) {
        float v = ecc_bias[o] + aggv;
#pragma unroll
        for (int i = 0; i < IN_C; i++) v += x[n * IN_C + i] * ecc_root[i * OUT_C + o];
        hv = fmaxf(v, 0.f);
    }

    float gv[4] = {0.f, 0.f, 0.f, 0.f};
#pragma unroll
    for (int k = 0; k < OUT_C; k++) {
        float hk = __shfl(hv, k);
#pragma unroll
        for (int j = 0; j < 4; j++)
            gv[j] += hk * gat_lin[k * GDIM + j * 64 + lane];
    }
#pragma unroll
    for (int j = 0; j < 4; j++)
        g_bf[(size_t)n * GDIM + j * 64 + lane] = f32_to_bf16(gv[j]);

    float vs[4], vd[4];
#pragma unroll
    for (int j = 0; j < 4; j++) {
        vs[j] = gv[j] * att_src_w[j * 64 + lane];
        vd[j] = gv[j] * att_dst_w[j * 64 + lane];
    }
#pragma unroll
    for (int off = 32; off; off >>= 1) {
#pragma unroll
        for (int j = 0; j < 4; j++) {
            vs[j] += __shfl_down(vs[j], off);
            vd[j] += __shfl_down(vd[j], off);
        }
    }
    if (lane == 0) {
#pragma unroll
        for (int j = 0; j < 4; j++) {
            asrc[n * HEADS + j] = vs[j];
            adst[n * HEADS + j] = vd[j];
        }
    }
}

// ---------- K_gat: single-pass fused softmax + aggregate ----------
__global__ __launch_bounds__(256) void k_gat(
    const int* __restrict__ offs, const int* __restrict__ src_csr,
    const float* __restrict__ asrc, const float* __restrict__ adst,
    const unsigned short* __restrict__ g_bf, unsigned short* __restrict__ outg)
{
    int n = blockIdx.x;
    int t = threadIdx.x;
    int beg = offs[n], deg = offs[n + 1] - beg;

    __shared__ float s_adst[HEADS];
    __shared__ float s_al[64 * HEADS];
    __shared__ int   s_sid[64];
    __shared__ float s_wsum[4][HEADS];
    __shared__ float s_den[HEADS];
    __shared__ float s_acc[8][GDIM];

    int j = t >> 2, h = t & 3;
    int lane32 = t & 31, grp = t >> 5;
    int myhead = lane32 >> 3;

    if (t < HEADS) s_adst[t] = adst[n * HEADS + t];
    __syncthreads();

    float acc[8];
#pragma unroll
    for (int k = 0; k < 8; k++) acc[k] = 0.f;
    float denp = 0.f;

    for (int c0 = 0; c0 < deg; c0 += 64) {
        int nc = min(64, deg - c0);
        if (j < nc) {
            int s = src_csr[beg + c0 + j];
            if (h == 0) s_sid[j] = s;
            float v = asrc[s * HEADS + h] + s_adst[h];
            v = v > 0.f ? v : NEG_SLOPE * v;
            float p = __expf(v);
            s_al[j * HEADS + h] = p;
            denp += p;
        }
        __syncthreads();
        for (int k8 = 0; k8 < nc; k8 += 8) {
            int e = k8 + grp;
            if (e < nc) {
                int s = s_sid[e];
                float a = s_al[e * HEADS + myhead];
                uint4 gv = *(const uint4*)&g_bf[(size_t)s * GDIM + lane32 * 8];
                acc[0] += a * bf16lo(gv.x);
                acc[1] += a * bf16hi(gv.x);
                acc[2] += a * bf16lo(gv.y);
                acc[3] += a * bf16hi(gv.y);
                acc[4] += a * bf16lo(gv.z);
                acc[5] += a * bf16hi(gv.z);
                acc[6] += a * bf16lo(gv.w);
                acc[7] += a * bf16hi(gv.w);
            }
        }
        __syncthreads();
    }

#pragma unroll
    for (int mask = 4; mask < 64; mask <<= 1) denp += __shfl_xor(denp, mask);
    if ((t & 63) < 4) s_wsum[t >> 6][t & 3] = denp;
#pragma unroll
    for (int k = 0; k < 8; k++) s_acc[grp][lane32 * 8 + k] = acc[k];
    __syncthreads();
    if (t < HEADS)
        s_den[t] = s_wsum[0][t] + s_wsum[1][t] + s_wsum[2][t] + s_wsum[3][t];
    __syncthreads();

    float v = 0.f;
#pragma unroll
    for (int gIdx = 0; gIdx < 8; gIdx++) v += s_acc[gIdx][t];
    int head = t >> 6;
    outg[(size_t)n * GDIM + t] = f32_to_bf16(v / (s_den[head] + 1e-16f));
}

// ---------- K6: y = relu(outg + gat_bias) @ fc_w + fc_b ----------
#define BM 64
#define BK6 16
__global__ __launch_bounds__(256) void k6_final(
    const unsigned short* __restrict__ outg, const float* __restrict__ gat_bias,
    const float* __restrict__ fc_w, const float* __restrict__ fc_b,
    float* __restrict__ y)
{
    __shared__ float sA[BK6][BM + 4];
    __shared__ float sW[BK6][FINAL];
    int tid = threadIdx.x;
    int r0 = blockIdx.x * BM;
    int tcol = (tid & 31) * 4;
    int trow = (tid >> 5) * 8;

    float acc[8][4];
#pragma unroll
    for (int r = 0; r < 8; r++)
#pragma unroll
        for (int c = 0; c < 4; c++) acc[r][c] = 0.f;

    int ar = tid >> 2;
    int ak = (tid & 3) * 4;

    for (int k0 = 0; k0 < GDIM; k0 += BK6) {
        int row = r0 + ar;
        float4 av = make_float4(0.f, 0.f, 0.f, 0.f);
        if (row < N_NODES) {
            uint2 raw = *(const uint2*)&outg[(size_t)row * GDIM + k0 + ak];
            av = make_float4(bf16lo(raw.x), bf16hi(raw.x), bf16lo(raw.y), bf16hi(raw.y));
        }
        float4 bv = *(const float4*)&gat_bias[k0 + ak];
        av.x = fmaxf(av.x + bv.x, 0.f);
        av.y = fmaxf(av.y + bv.y, 0.f);
        av.z = fmaxf(av.z + bv.z, 0.f);
        av.w = fmaxf(av.w + bv.w, 0.f);
        sA[ak + 0][ar] = av.x;
        sA[ak + 1][ar] = av.y;
        sA[ak + 2][ar] = av.z;
        sA[ak + 3][ar] = av.w;
#pragma unroll
        for (int p = 0; p < 2; p++) {
            int kk = (tid >> 5) + p * 8;
            int c = (tid & 31) * 4;
            *(float4*)&sW[kk][c] = *(const float4*)&fc_w[(size_t)(k0 + kk) * FINAL + c];
        }
        __syncthreads();
#pragma unroll
        for (int kk = 0; kk < BK6; kk++) {
            float4 w = *(const float4*)&sW[kk][tcol];
            float4 a0 = *(const float4*)&sA[kk][trow];
            float4 a1 = *(const float4*)&sA[kk][trow + 4];
            float a[8] = {a0.x, a0.y, a0.z, a0.w, a1.x, a1.y, a1.z, a1.w};
#pragma unroll
            for (int r = 0; r < 8; r++) {
                acc[r][0] += a[r] * w.x;
                acc[r][1] += a[r] * w.y;
                acc[r][2] += a[r] * w.z;
                acc[r][3] += a[r] * w.w;
            }
        }
        __syncthreads();
    }

    float4 fb = *(const float4*)&fc_b[tcol];
#pragma unroll
    for (int r = 0; r < 8; r++) {
        int row = r0 + trow + r;
        if (row < N_NODES) {
            *(float4*)&y[(size_t)row * FINAL + tcol] =
                make_float4(acc[r][0] + fb.x, acc[r][1] + fb.y,
                            acc[r][2] + fb.z, acc[r][3] + fb.w);
        }
    }
}

extern "C" void kernel_launch(void* const* d_in, const int* in_sizes, int n_in,
                              void* d_out, int out_size, void* d_ws, size_t ws_size,
                              hipStream_t stream)
{
    const float* x        = (const float*)d_in[0];
    const int*   ei       = (const int*)d_in[1];
    const float* ea       = (const float*)d_in[2];
    const float* ecc_root = (const float*)d_in[3];
    const float* ecc_bias = (const float*)d_in[4];
    const float* mlp_w    = (const float*)d_in[5];
    const float* mlp_b    = (const float*)d_in[6];
    const float* gat_lin  = (const float*)d_in[7];
    const float* att_src  = (const float*)d_in[8];
    const float* att_dst  = (const float*)d_in[9];
    const float* gat_bias = (const float*)d_in[10];
    const float* fc_w     = (const float*)d_in[11];
    const float* fc_b     = (const float*)d_in[12];
    float* y = (float*)d_out;

    const int* src = ei;
    const int* dst = ei + N_EDGES;

    // workspace layout
    float* ea_csr = (float*)d_ws;                                        // E*8 fp32 (25.6 MB)
    uint4* Y4     = (uint4*)(ea_csr + (size_t)N_EDGES * EDGE_F);         // N*16 uint4 (12.8 MB)
    float* z      = (float*)(Y4 + (size_t)N_NODES * OUT_C);              // N*16 fp32 (3.2 MB)
    unsigned short* g_bf = (unsigned short*)(z + (size_t)N_NODES * OUT_C); // N*256 bf16 (25.6 MB)
    float* asrc   = (float*)(g_bf + (size_t)N_NODES * GDIM);             // N*4
    float* adst   = asrc + (size_t)N_NODES * HEADS;                      // N*4
    int*   cnt      = (int*)(adst + (size_t)N_NODES * HEADS);            // N
    int*   offs     = cnt + N_NODES;                                     // N+1
    int*   part     = offs + N_NODES + 1;                                // 256
    int*   partscan = part + 256;                                        // 256
    int*   rnk      = partscan + 256;                                    // E
    int*   src_csr  = rnk + N_EDGES;                                     // E
    unsigned short* outg = (unsigned short*)ea_csr;  // alias: ea_csr dead after k2c

    hipMemsetAsync(cnt, 0, sizeof(int) * N_NODES, stream);

    int eb = (N_EDGES + 255) / 256;
    k_hist   <<<eb, 256, 0, stream>>>(dst, cnt, rnk);
    k_part   <<<NBLK, 256, 0, stream>>>(cnt, part);
    k_scan1  <<<1, 256, 0, stream>>>(part, partscan);
    k_add    <<<NBLK, 256, 0, stream>>>(cnt, partscan, offs);

    k0_y     <<<(N_NODES * 16 + 255) / 256, 256, 0, stream>>>(x, mlp_w, mlp_b, Y4, z);
    k_prep   <<<eb, 256, 0, stream>>>(src, dst, rnk, offs, ea, src_csr, ea_csr);
    k2c_node <<<(N_NODES + 3) / 4, 256, 0, stream>>>(x, Y4, z, offs, src_csr,
                                                     (const float4*)ea_csr,
                                                     ecc_root, ecc_bias, gat_lin,
                                                     att_src, att_dst, g_bf, asrc, adst);
    k_gat    <<<N_NODES, 256, 0, stream>>>(offs, src_csr, asrc, adst, g_bf, outg);
    k6_final <<<(N_NODES + BM - 1) / BM, 256, 0, stream>>>(outg, gat_bias, fc_w, fc_b, y);
}